// Round 8
// baseline (585.361 us; speedup 1.0000x reference)
//
#include <hip/hip_runtime.h>

typedef __bf16 bf16x8 __attribute__((ext_vector_type(8)));
typedef float  f32x4  __attribute__((ext_vector_type(4)));
typedef unsigned int u32x4 __attribute__((ext_vector_type(4)));

#define LDA 136       // padded bf16 row stride for GEMM LDS tiles
#define NB_MAX 1024   // max 128-node buckets (N<=131072)
#define SREP 32       // stats replication factor (spreads atomic contention)

static __device__ __forceinline__ unsigned short f2bf(float f) {
  unsigned int u = __float_as_uint(f);
  u += 0x7fffu + ((u >> 16) & 1u);
  return (unsigned short)(u >> 16);
}
static __device__ __forceinline__ float bflo(unsigned int u) {
  return __uint_as_float(u << 16);
}
static __device__ __forceinline__ float bfhi(unsigned int u) {
  return __uint_as_float(u & 0xFFFF0000u);
}
static __device__ __forceinline__ unsigned int packbf2(float a, float b) {
  return (unsigned int)f2bf(a) | ((unsigned int)f2bf(b) << 16);
}
// non-temporal 16B helpers (evict-first hint; read-once / write-once streams)
static __device__ __forceinline__ u32x4 ntload4(const void* p) {
  return __builtin_nontemporal_load((const u32x4*)p);
}
static __device__ __forceinline__ void ntstore4(void* p, u32x4 v) {
  __builtin_nontemporal_store(v, (u32x4*)p);
}

// ---------- fused prep (weights->bf16, zero stats) + bucket histogram --------
// blocks 0..255: histogram chunks; blocks 256..327: prep work
__global__ void prep_hist(const float* __restrict__ W1, const float* __restrict__ W2,
                          const float* __restrict__ W3, unsigned short* __restrict__ w1b,
                          unsigned short* __restrict__ w2b, unsigned short* __restrict__ w3b,
                          float* __restrict__ s1, float* __restrict__ s2,
                          const int* __restrict__ ei, int* __restrict__ bhist,
                          int E, int NB) {
  __shared__ int h[NB_MAX];
  const int blk = blockIdx.x;
  if (blk >= 256) {  // prep branch (uniform per block; no barrier divergence)
    int i = (blk - 256) * 256 + threadIdx.x;
    if (i < SREP * 256) { s1[i] = 0.f; s2[i] = 0.f; }
    if (i < 16384) {
      w1b[i] = f2bf(W1[i]);
      w2b[i] = f2bf(W2[i]);
    } else if (i < 18432) {
      int j = i - 16384;  // 16x128 padded W3
      w3b[j] = (j < 1280) ? f2bf(W3[j]) : 0;
    }
    return;
  }
  for (int i = threadIdx.x; i < NB; i += blockDim.x) h[i] = 0;
  __syncthreads();
  int chunk = (E + 255) / 256;
  int e0 = blk * chunk;
  int e1 = min(e0 + chunk, E);
  for (int e = e0 + (int)threadIdx.x; e < e1; e += blockDim.x)
    atomicAdd(&h[ei[E + e] >> 7], 1);
  __syncthreads();
  for (int i = threadIdx.x; i < NB; i += blockDim.x)
    bhist[blk * NB + i] = h[i];
}

// ---------- fp32 -> bf16 cast (NT input reads; output is next gather table) --
__global__ void cvt_bf16(const float* __restrict__ x,
                         unsigned short* __restrict__ o, long long n) {
  long long i = ((long long)blockIdx.x * blockDim.x + threadIdx.x) * 4;
  if (i < n) {
    u32x4 r = ntload4(x + i);
    uint2 w;
    w.x = packbf2(__uint_as_float(r.x), __uint_as_float(r.y));
    w.y = packbf2(__uint_as_float(r.z), __uint_as_float(r.w));
    *(uint2*)(o + i) = w;
  }
}

// ---------- reduce replicated stats -> BN coefficients (one block) -----------
__global__ void __launch_bounds__(128)
bn_coef(const float* __restrict__ stats, const float* __restrict__ g,
        const float* __restrict__ be, float* __restrict__ coef, float invN) {
  int f = threadIdx.x;
  float sum = 0.f, sq = 0.f;
  for (int r = 0; r < SREP; ++r) {
    sum += stats[r * 256 + f];
    sq  += stats[r * 256 + 128 + f];
  }
  float mean = sum * invN;
  float var = sq * invN - mean * mean;
  float s = g[f] * rsqrtf(var + 1e-5f);
  coef[f] = s;
  coef[128 + f] = be[f] - mean * s;
}

// ---------- column scan: per-bucket exclusive scan over the 256 chunks -------
__global__ void __launch_bounds__(256)
colscan(const int* __restrict__ bhist, int* __restrict__ cbase,
        int* __restrict__ bcnt, int NB) {
  __shared__ int tmp[256];
  const int b = blockIdx.x;
  const int g = threadIdx.x;
  int v = bhist[g * NB + b];
  tmp[g] = v;
  __syncthreads();
  for (int off = 1; off < 256; off <<= 1) {
    int t = (g >= off) ? tmp[g - off] : 0;
    __syncthreads();
    tmp[g] += t;
    __syncthreads();
  }
  cbase[g * NB + b] = tmp[g] - v;  // exclusive
  if (g == 255) bcnt[b] = tmp[255];
}

// ---------- scan bucket counts (NB<=1024, single chunk) ----------
__global__ void scan_buckets(const int* __restrict__ cnt,
                             int* __restrict__ bstart, int n) {
  __shared__ int tmp[1024];
  int i = threadIdx.x;
  int v = (i < n) ? cnt[i] : 0;
  tmp[i] = v;
  __syncthreads();
  for (int off = 1; off < 1024; off <<= 1) {
    int t = (i >= off) ? tmp[i - off] : 0;
    __syncthreads();
    tmp[i] += t;
    __syncthreads();
  }
  if (i == 0) bstart[0] = 0;
  if (i < n) bstart[i + 1] = tmp[i];
}

// ---------- partition edges; block base from cbase (deterministic, 0 atomics)
__global__ void partition_edges(const int* __restrict__ ei,
                                const int* __restrict__ bstart,
                                const int* __restrict__ cbase,
                                unsigned int* __restrict__ part, int E, int NB) {
  __shared__ int base[NB_MAX];
  __shared__ int cur[NB_MAX];
  int chunk = (E + gridDim.x - 1) / gridDim.x;
  int e0 = blockIdx.x * chunk;
  int e1 = min(e0 + chunk, E);
  for (int i = threadIdx.x; i < NB; i += blockDim.x) {
    cur[i] = 0;
    base[i] = bstart[i] + cbase[blockIdx.x * NB + i];
  }
  __syncthreads();
  for (int e = e0 + (int)threadIdx.x; e < e1; e += blockDim.x) {
    int d = ei[E + e];
    int b = d >> 7;
    int slot = base[b] + atomicAdd(&cur[b], 1);
    part[slot] = (unsigned int)ei[e] | ((unsigned int)(d & 127) << 17);
  }
}

// ---------- counting-sort each bucket -> csr + rs ----------
__global__ void __launch_bounds__(256)
csr_fill(const unsigned int* __restrict__ part, const int* __restrict__ bstart,
         int* __restrict__ rs, int* __restrict__ csr, int N, int NB) {
  __shared__ int h[128];
  __shared__ int off[128];
  const int b = blockIdx.x;
  const int e0 = bstart[b], e1 = bstart[b + 1];
  const int tid = threadIdx.x;
  if (tid < 128) h[tid] = 0;
  __syncthreads();
  for (int i = e0 + tid; i < e1; i += 256)
    atomicAdd(&h[part[i] >> 17], 1);
  __syncthreads();
  if (tid < 128) off[tid] = h[tid];
  __syncthreads();
  for (int s = 1; s < 128; s <<= 1) {
    int v = (tid < 128 && tid >= s) ? off[tid - s] : 0;
    __syncthreads();
    if (tid < 128) off[tid] += v;
    __syncthreads();
  }
  if (tid < 128) {
    int excl = e0 + off[tid] - h[tid];
    int node = b * 128 + tid;
    if (node < N) rs[node] = excl;
    h[tid] = excl;  // reuse as cursor
  }
  if (b == NB - 1 && tid == 0) rs[N] = e1;
  __syncthreads();
  for (int i = e0 + tid; i < e1; i += 256) {
    unsigned int p = part[i];
    int slot = atomicAdd(&h[p >> 17], 1);
    csr[slot] = (int)(p & 0x1FFFF);
  }
}

// ---------- aggregation: agg[i] = t[i] + sum_j t[j], bf16, fp32 acc ----------
// one wave per node; 16 lanes x 16B cover a row; NT on csr reads + output
// stores so the gather table keeps the L2 to itself.
__global__ void __launch_bounds__(256)
csr_agg128(const unsigned short* __restrict__ t, const int* __restrict__ rs,
           const int* __restrict__ csr, unsigned short* __restrict__ agg,
           int N) {
  int node = blockIdx.x * 4 + (threadIdx.x >> 6);
  if (node >= N) return;
  const int lane = threadIdx.x & 63;
  const int q = lane >> 4;   // quarter 0..3 -> edge stride phase
  const int ql = lane & 15;  // lane within quarter
  const int c = ql * 8;      // bf16 column (16B per lane)
  float a0 = 0.f, a1 = 0.f, a2 = 0.f, a3 = 0.f;
  float a4 = 0.f, a5 = 0.f, a6 = 0.f, a7 = 0.f;
  const int b = rs[node], e = rs[node + 1];
  int i = b + q;
  for (; i + 4 < e; i += 8) {  // 2 independent 1KB gathers in flight
    int j0 = __builtin_nontemporal_load(csr + i);
    int j1 = __builtin_nontemporal_load(csr + i + 4);
    uint4 v0 = *(const uint4*)(t + (long long)j0 * 128 + c);
    uint4 v1 = *(const uint4*)(t + (long long)j1 * 128 + c);
    a0 += bflo(v0.x) + bflo(v1.x);  a1 += bfhi(v0.x) + bfhi(v1.x);
    a2 += bflo(v0.y) + bflo(v1.y);  a3 += bfhi(v0.y) + bfhi(v1.y);
    a4 += bflo(v0.z) + bflo(v1.z);  a5 += bfhi(v0.z) + bfhi(v1.z);
    a6 += bflo(v0.w) + bflo(v1.w);  a7 += bfhi(v0.w) + bfhi(v1.w);
  }
  if (i < e) {
    int j = __builtin_nontemporal_load(csr + i);
    uint4 v = *(const uint4*)(t + (long long)j * 128 + c);
    a0 += bflo(v.x);  a1 += bfhi(v.x);
    a2 += bflo(v.y);  a3 += bfhi(v.y);
    a4 += bflo(v.z);  a5 += bfhi(v.z);
    a6 += bflo(v.w);  a7 += bfhi(v.w);
  }
  a0 += __shfl_xor(a0, 16, 64);  a1 += __shfl_xor(a1, 16, 64);
  a2 += __shfl_xor(a2, 16, 64);  a3 += __shfl_xor(a3, 16, 64);
  a4 += __shfl_xor(a4, 16, 64);  a5 += __shfl_xor(a5, 16, 64);
  a6 += __shfl_xor(a6, 16, 64);  a7 += __shfl_xor(a7, 16, 64);
  a0 += __shfl_xor(a0, 32, 64);  a1 += __shfl_xor(a1, 32, 64);
  a2 += __shfl_xor(a2, 32, 64);  a3 += __shfl_xor(a3, 32, 64);
  a4 += __shfl_xor(a4, 32, 64);  a5 += __shfl_xor(a5, 32, 64);
  a6 += __shfl_xor(a6, 32, 64);  a7 += __shfl_xor(a7, 32, 64);
  if (q == 0) {
    uint4 sv = *(const uint4*)(t + (long long)node * 128 + c);  // self term
    u32x4 w;
    w.x = packbf2(a0 + bflo(sv.x), a1 + bfhi(sv.x));
    w.y = packbf2(a2 + bflo(sv.y), a3 + bfhi(sv.y));
    w.z = packbf2(a4 + bflo(sv.z), a5 + bfhi(sv.z));
    w.w = packbf2(a6 + bflo(sv.w), a7 + bfhi(sv.w));
    ntstore4(agg + (long long)node * 128 + c, w);
  }
}

// ---------- fused: agg[i] = relu(bn(h_i)) + sum_j relu(bn(h_j)) --------------
// BN coefficients precomputed by bn_coef (no per-block reduction)
__global__ void __launch_bounds__(256)
csr_agg128_bn(const unsigned short* __restrict__ t, const int* __restrict__ rs,
              const int* __restrict__ csr, const float* __restrict__ coef,
              unsigned short* __restrict__ agg, int N) {
  __shared__ float lsc[128], lsh[128];
  if (threadIdx.x < 128) {
    lsc[threadIdx.x] = coef[threadIdx.x];
    lsh[threadIdx.x] = coef[128 + threadIdx.x];
  }
  __syncthreads();
  int node = blockIdx.x * 4 + (threadIdx.x >> 6);
  if (node >= N) return;
  const int lane = threadIdx.x & 63;
  const int q = lane >> 4;
  const int ql = lane & 15;
  const int c = ql * 8;
  float sc0 = lsc[c], sc1 = lsc[c + 1], sc2 = lsc[c + 2], sc3 = lsc[c + 3];
  float sc4 = lsc[c + 4], sc5 = lsc[c + 5], sc6 = lsc[c + 6], sc7 = lsc[c + 7];
  float sh0 = lsh[c], sh1 = lsh[c + 1], sh2 = lsh[c + 2], sh3 = lsh[c + 3];
  float sh4 = lsh[c + 4], sh5 = lsh[c + 5], sh6 = lsh[c + 6], sh7 = lsh[c + 7];
  float a0 = 0.f, a1 = 0.f, a2 = 0.f, a3 = 0.f;
  float a4 = 0.f, a5 = 0.f, a6 = 0.f, a7 = 0.f;
  const int b = rs[node], e = rs[node + 1];
  for (int i = b + q; i < e; i += 4) {
    int j = __builtin_nontemporal_load(csr + i);
    uint4 v = *(const uint4*)(t + (long long)j * 128 + c);
    a0 += fmaxf(fmaf(bflo(v.x), sc0, sh0), 0.f);
    a1 += fmaxf(fmaf(bfhi(v.x), sc1, sh1), 0.f);
    a2 += fmaxf(fmaf(bflo(v.y), sc2, sh2), 0.f);
    a3 += fmaxf(fmaf(bfhi(v.y), sc3, sh3), 0.f);
    a4 += fmaxf(fmaf(bflo(v.z), sc4, sh4), 0.f);
    a5 += fmaxf(fmaf(bfhi(v.z), sc5, sh5), 0.f);
    a6 += fmaxf(fmaf(bflo(v.w), sc6, sh6), 0.f);
    a7 += fmaxf(fmaf(bfhi(v.w), sc7, sh7), 0.f);
  }
  a0 += __shfl_xor(a0, 16, 64);  a1 += __shfl_xor(a1, 16, 64);
  a2 += __shfl_xor(a2, 16, 64);  a3 += __shfl_xor(a3, 16, 64);
  a4 += __shfl_xor(a4, 16, 64);  a5 += __shfl_xor(a5, 16, 64);
  a6 += __shfl_xor(a6, 16, 64);  a7 += __shfl_xor(a7, 16, 64);
  a0 += __shfl_xor(a0, 32, 64);  a1 += __shfl_xor(a1, 32, 64);
  a2 += __shfl_xor(a2, 32, 64);  a3 += __shfl_xor(a3, 32, 64);
  a4 += __shfl_xor(a4, 32, 64);  a5 += __shfl_xor(a5, 32, 64);
  a6 += __shfl_xor(a6, 32, 64);  a7 += __shfl_xor(a7, 32, 64);
  if (q == 0) {
    uint4 sv = *(const uint4*)(t + (long long)node * 128 + c);  // self, affine
    u32x4 w;
    w.x = packbf2(a0 + fmaxf(fmaf(bflo(sv.x), sc0, sh0), 0.f),
                  a1 + fmaxf(fmaf(bfhi(sv.x), sc1, sh1), 0.f));
    w.y = packbf2(a2 + fmaxf(fmaf(bflo(sv.y), sc2, sh2), 0.f),
                  a3 + fmaxf(fmaf(bfhi(sv.y), sc3, sh3), 0.f));
    w.z = packbf2(a4 + fmaxf(fmaf(bflo(sv.z), sc4, sh4), 0.f),
                  a5 + fmaxf(fmaf(bfhi(sv.z), sc5, sh5), 0.f));
    w.w = packbf2(a6 + fmaxf(fmaf(bflo(sv.w), sc6, sh6), 0.f),
                  a7 + fmaxf(fmaf(bfhi(sv.w), sc7, sh7), 0.f));
    ntstore4(agg + (long long)node * 128 + c, w);
  }
}

// ---------- layer-3 aggregation on bf16 y[N,16] (8 lanes/node) ----------
__global__ void __launch_bounds__(256)
csr_agg10b(const unsigned short* __restrict__ y, const int* __restrict__ rs,
           const int* __restrict__ csr, const float* __restrict__ b3,
           float* __restrict__ out, int N) {
  int t = blockIdx.x * blockDim.x + threadIdx.x;
  int node = t >> 3;
  int c = (t & 7) * 2;
  if (node >= N) return;
  unsigned int sv = *(const unsigned int*)(y + node * 16 + c);
  float a0 = bflo(sv), a1 = bfhi(sv);
  int b = rs[node], e = rs[node + 1];
  int i = b;
  for (; i + 3 < e; i += 4) {
    int j0 = __builtin_nontemporal_load(csr + i);
    int j1 = __builtin_nontemporal_load(csr + i + 1);
    int j2 = __builtin_nontemporal_load(csr + i + 2);
    int j3 = __builtin_nontemporal_load(csr + i + 3);
    unsigned int v0 = *(const unsigned int*)(y + j0 * 16 + c);
    unsigned int v1 = *(const unsigned int*)(y + j1 * 16 + c);
    unsigned int v2 = *(const unsigned int*)(y + j2 * 16 + c);
    unsigned int v3 = *(const unsigned int*)(y + j3 * 16 + c);
    a0 += bflo(v0) + bflo(v1) + bflo(v2) + bflo(v3);
    a1 += bfhi(v0) + bfhi(v1) + bfhi(v2) + bfhi(v3);
  }
  for (; i < e; ++i) {
    unsigned int v = *(const unsigned int*)(y + csr[i] * 16 + c);
    a0 += bflo(v);
    a1 += bfhi(v);
  }
  if (c < 10) {
    float2 o;
    o.x = a0 + b3[c];
    o.y = a1 + b3[c + 1];
    *(float2*)(out + node * 10 + c) = o;  // 40*node+8*(c/2): 8B aligned
  }
}

// ---------- GEMM: h_bf16 = A_bf16 @ Wb^T + bias, fused BN stats --------------
// stats into SREP-replicated buffers; A-reads NT (aggb is dead afterwards)
__global__ void __launch_bounds__(256)
gemm128(const unsigned short* __restrict__ Ab, const unsigned short* __restrict__ Wb,
        const float* __restrict__ bias, unsigned short* __restrict__ Hb,
        float* __restrict__ stats, int M) {
  __shared__ __align__(16) unsigned short sA[128 * LDA];
  __shared__ __align__(16) unsigned short sB[128 * LDA];
  __shared__ float sSum[128], sSq[128];
  const int tid = threadIdx.x;
  const int row0 = blockIdx.x * 128;

  if (tid < 128) { sSum[tid] = 0.f; sSq[tid] = 0.f; }
  for (int j = 0; j < 8; ++j) {
    int flat = j * 2048 + tid * 8;
    int r = flat >> 7, c = flat & 127;
    int gr = row0 + r;
    u32x4 v = {0, 0, 0, 0};
    if (gr < M) v = ntload4(Ab + (long long)gr * 128 + c);
    *(u32x4*)(sA + r * LDA + c) = v;
  }
  for (int j = 0; j < 8; ++j) {  // W already bf16: straight copies
    int flat = j * 2048 + tid * 8;
    int r = flat >> 7, c = flat & 127;
    *(uint4*)(sB + r * LDA + c) = *(const uint4*)(Wb + flat);
  }
  __syncthreads();

  const int lane = tid & 63, wid = tid >> 6;
  const int wM = (wid >> 1) * 64, wN = (wid & 1) * 64;
  const int l15 = lane & 15, quad = lane >> 4;
  f32x4 acc[4][4] = {};

  for (int kk = 0; kk < 4; ++kk) {
    const int kb = kk * 32 + quad * 8;
    bf16x8 af[4], bfr[4];
    for (int mi = 0; mi < 4; ++mi)
      af[mi] = *reinterpret_cast<const bf16x8*>(sA + (wM + mi * 16 + l15) * LDA + kb);
    for (int ni = 0; ni < 4; ++ni)
      bfr[ni] = *reinterpret_cast<const bf16x8*>(sB + (wN + ni * 16 + l15) * LDA + kb);
    for (int mi = 0; mi < 4; ++mi)
      for (int ni = 0; ni < 4; ++ni)
        acc[mi][ni] = __builtin_amdgcn_mfma_f32_16x16x32_bf16(
            af[mi], bfr[ni], acc[mi][ni], 0, 0, 0);
  }
  __syncthreads();  // done with sA as A-tile; reuse as C staging

  for (int ni = 0; ni < 4; ++ni) {
    int col = wN + ni * 16 + l15;
    float bv = bias[col];
    float s = 0.f, q = 0.f;
    for (int mi = 0; mi < 4; ++mi) {
      int rloc = wM + mi * 16 + quad * 4;
      for (int r = 0; r < 4; ++r) {
        if (row0 + rloc + r < M) {
          float v = acc[mi][ni][r] + bv;
          sA[(rloc + r) * LDA + col] = f2bf(v);
          s += v;
          q += v * v;
        }
      }
    }
    atomicAdd(&sSum[col], s);
    atomicAdd(&sSq[col], q);
  }
  __syncthreads();
  if (tid < 128) {
    float* st = stats + ((blockIdx.x & (SREP - 1)) << 8);
    atomicAdd(&st[tid], sSum[tid]);
    atomicAdd(&st[128 + tid], sSq[tid]);
  }
  for (int j = 0; j < 8; ++j) {  // coalesced 16B stores (Hb = next gather table)
    int flat = j * 2048 + tid * 8;
    int r = flat >> 7, c = flat & 127;
    int gr = row0 + r;
    if (gr < M)
      *(uint4*)(Hb + (long long)gr * 128 + c) = *(const uint4*)(sA + r * LDA + c);
  }
}

// ---------- y = relu(bn(h)) @ w3b^T, affine (from coef) fused into A-staging -
__global__ void __launch_bounds__(256)
gemm_y_bn(const unsigned short* __restrict__ Hb, const unsigned short* __restrict__ w3b,
          const float* __restrict__ coef, unsigned short* __restrict__ Y, int M) {
  __shared__ __align__(16) unsigned short sA[128 * LDA];
  __shared__ __align__(16) unsigned short sB[16 * LDA];
  __shared__ float lsc[128], lsh[128];
  const int tid = threadIdx.x;
  const int row0 = blockIdx.x * 128;

  if (tid < 128) {
    lsc[tid] = coef[tid];
    lsh[tid] = coef[128 + tid];
  }
  __syncthreads();
  for (int j = 0; j < 8; ++j) {
    int flat = j * 2048 + tid * 8;
    int r = flat >> 7, c = flat & 127;
    int gr = row0 + r;
    u32x4 v = {0, 0, 0, 0};
    if (gr < M) v = ntload4(Hb + (long long)gr * 128 + c);  // hb dead after this
    uint4 w;
    w.x = packbf2(fmaxf(fmaf(bflo(v.x), lsc[c + 0], lsh[c + 0]), 0.f),
                  fmaxf(fmaf(bfhi(v.x), lsc[c + 1], lsh[c + 1]), 0.f));
    w.y = packbf2(fmaxf(fmaf(bflo(v.y), lsc[c + 2], lsh[c + 2]), 0.f),
                  fmaxf(fmaf(bfhi(v.y), lsc[c + 3], lsh[c + 3]), 0.f));
    w.z = packbf2(fmaxf(fmaf(bflo(v.z), lsc[c + 4], lsh[c + 4]), 0.f),
                  fmaxf(fmaf(bfhi(v.z), lsc[c + 5], lsh[c + 5]), 0.f));
    w.w = packbf2(fmaxf(fmaf(bflo(v.w), lsc[c + 6], lsh[c + 6]), 0.f),
                  fmaxf(fmaf(bfhi(v.w), lsc[c + 7], lsh[c + 7]), 0.f));
    *(uint4*)(sA + r * LDA + c) = w;
  }
  {
    int flat = tid * 8;
    int r = flat >> 7, c = flat & 127;
    *(uint4*)(sB + r * LDA + c) = *(const uint4*)(w3b + flat);
  }
  __syncthreads();

  const int lane = tid & 63, wid = tid >> 6;
  const int l15 = lane & 15, quad = lane >> 4;
  f32x4 acc[2] = {};
  for (int kk = 0; kk < 4; ++kk) {
    const int kb = kk * 32 + quad * 8;
    bf16x8 b = *reinterpret_cast<const bf16x8*>(sB + l15 * LDA + kb);
    for (int mi = 0; mi < 2; ++mi) {
      bf16x8 a = *reinterpret_cast<const bf16x8*>(
          sA + (wid * 32 + mi * 16 + l15) * LDA + kb);
      acc[mi] = __builtin_amdgcn_mfma_f32_16x16x32_bf16(a, b, acc[mi], 0, 0, 0);
    }
  }
  __syncthreads();  // reuse sA as 128x16 C staging (stride 16)
  for (int mi = 0; mi < 2; ++mi)
    for (int r = 0; r < 4; ++r) {
      int rloc = wid * 32 + mi * 16 + quad * 4 + r;
      sA[rloc * 16 + l15] = (l15 < 10) ? f2bf(acc[mi][r]) : 0;
    }
  __syncthreads();
  {
    int flat = tid * 8;
    int gr = row0 + (flat >> 4);
    if (gr < M) *(uint4*)(Y + (long long)gr * 16 + (flat & 15)) =
        *(const uint4*)(sA + flat);  // y = next gather table: cached store
  }
}

// ---------- host ----------
extern "C" void kernel_launch(void* const* d_in, const int* in_sizes, int n_in,
                              void* d_out, int out_size, void* d_ws,
                              size_t ws_size, hipStream_t stream) {
  const float* x  = (const float*)d_in[0];
  const int*   ei = (const int*)d_in[1];  // int32 per harness contract
  const float* W1 = (const float*)d_in[2];
  const float* b1 = (const float*)d_in[3];
  const float* g1 = (const float*)d_in[4];
  const float* be1 = (const float*)d_in[5];
  const float* W2 = (const float*)d_in[6];
  const float* b2 = (const float*)d_in[7];
  const float* g2 = (const float*)d_in[8];
  const float* be2 = (const float*)d_in[9];
  const float* W3 = (const float*)d_in[10];
  const float* b3 = (const float*)d_in[11];

  const int N = in_sizes[0] / 128;
  const int E = in_sizes[1] / 2;
  const int NB = (N + 127) / 128;  // 128-node buckets

  // workspace layout (~91 MB); 16B-aligned arrays first
  unsigned short* featb = (unsigned short*)d_ws;              // N*128 bf16
  unsigned short* aggb  = featb + (size_t)N * 128;            // N*128 bf16
  unsigned short* hb    = aggb + (size_t)N * 128;             // N*128 bf16
  unsigned short* w1b   = hb + (size_t)N * 128;               // 16384
  unsigned short* w2b   = w1b + 16384;                        // 16384
  unsigned short* w3b   = w2b + 16384;                        // 2048
  int*   csr = (int*)(w3b + 2048);                            // E ints
  int*   rs  = csr + E;                                       // N+1
  int* bcnt  = rs + N + 1;                                    // NB
  int* bstart = bcnt + NB;                                    // NB+1
  int* bhist = bstart + NB + 1;                               // 256*NB
  float* stats1 = (float*)(bhist + 256 * NB);                 // SREP*256
  float* stats2 = stats1 + SREP * 256;                        // SREP*256
  float* coef1  = stats2 + SREP * 256;                        // 256
  float* coef2  = coef1 + 256;                                // 256
  // aliases into the (currently dead) hb region:
  unsigned int* part = (unsigned int*)hb;             // E uints (12.8 MB)
  int* cbase = (int*)(hb + (size_t)E * 2);            // 256*NB ints (~0.8 MB)
  unsigned short* y = featb;  // aliases featb (free in layer 3)
  float* out = (float*)d_out;

  const int TPB = 256;
  const int cvtBlocks   = (int)(((long long)N * 32 + TPB - 1) / TPB);
  const int aggBlocks   = (N + 3) / 4;   // one wave per node
  const int agg10Blocks = (N * 8 + TPB - 1) / TPB;
  const int gemmBlocks  = (N + 127) / 128;
  const float invN = 1.0f / (float)N;

  // ---- build: weights + CSR (atomic-free global phase) ----
  prep_hist<<<328, TPB, 0, stream>>>(W1, W2, W3, w1b, w2b, w3b, stats1, stats2,
                                     ei, bhist, E, NB);
  colscan<<<NB, TPB, 0, stream>>>(bhist, cbase, bcnt, NB);
  scan_buckets<<<1, 1024, 0, stream>>>(bcnt, bstart, NB);
  partition_edges<<<256, TPB, 0, stream>>>(ei, bstart, cbase, part, E, NB);
  csr_fill<<<NB, TPB, 0, stream>>>(part, bstart, rs, csr, N, NB);

  // ---- layer 1 ----
  cvt_bf16<<<cvtBlocks, TPB, 0, stream>>>(x, featb, (long long)N * 128);
  csr_agg128<<<aggBlocks, TPB, 0, stream>>>(featb, rs, csr, aggb, N);
  gemm128<<<gemmBlocks, TPB, 0, stream>>>(aggb, w1b, b1, hb, stats1, N);

  // ---- layer 2 (BN1 coefficients reduced once; BN+ReLU fused into agg) ----
  bn_coef<<<1, 128, 0, stream>>>(stats1, g1, be1, coef1, invN);
  csr_agg128_bn<<<aggBlocks, TPB, 0, stream>>>(hb, rs, csr, coef1, aggb, N);
  gemm128<<<gemmBlocks, TPB, 0, stream>>>(aggb, w2b, b2, hb, stats2, N);

  // ---- layer 3 (BN2 via coef; BN+ReLU fused into gemm_y A-staging) ----
  bn_coef<<<1, 128, 0, stream>>>(stats2, g2, be2, coef2, invN);
  gemm_y_bn<<<gemmBlocks, TPB, 0, stream>>>(hb, w3b, coef2, y, N);
  csr_agg10b<<<agg10Blocks, TPB, 0, stream>>>(y, rs, csr, b3, out, N);
}

// Round 9
// 554.508 us; speedup vs baseline: 1.0556x; 1.0556x over previous
//
#include <hip/hip_runtime.h>

typedef __bf16 bf16x8 __attribute__((ext_vector_type(8)));
typedef float  f32x4  __attribute__((ext_vector_type(4)));

#define LDA 136       // padded bf16 row stride for GEMM LDS tiles
#define NB_MAX 1024   // max 128-node buckets (N<=131072)
#define SREP 32       // stats replication factor (spreads atomic contention)

static __device__ __forceinline__ unsigned short f2bf(float f) {
  unsigned int u = __float_as_uint(f);
  u += 0x7fffu + ((u >> 16) & 1u);
  return (unsigned short)(u >> 16);
}
static __device__ __forceinline__ float bflo(unsigned int u) {
  return __uint_as_float(u << 16);
}
static __device__ __forceinline__ float bfhi(unsigned int u) {
  return __uint_as_float(u & 0xFFFF0000u);
}
static __device__ __forceinline__ unsigned int packbf2(float a, float b) {
  return (unsigned int)f2bf(a) | ((unsigned int)f2bf(b) << 16);
}

// ---------- fused prep (weights->bf16, zero stats) + bucket histogram --------
// blocks 0..255: histogram chunks; blocks 256..327: prep work
__global__ void prep_hist(const float* __restrict__ W1, const float* __restrict__ W2,
                          const float* __restrict__ W3, unsigned short* __restrict__ w1b,
                          unsigned short* __restrict__ w2b, unsigned short* __restrict__ w3b,
                          float* __restrict__ s1, float* __restrict__ s2,
                          const int* __restrict__ ei, int* __restrict__ bhist,
                          int E, int NB) {
  __shared__ int h[NB_MAX];
  const int blk = blockIdx.x;
  if (blk >= 256) {  // prep branch (uniform per block; no barrier divergence)
    int i = (blk - 256) * 256 + threadIdx.x;
    if (i < SREP * 256) { s1[i] = 0.f; s2[i] = 0.f; }
    if (i < 16384) {
      w1b[i] = f2bf(W1[i]);
      w2b[i] = f2bf(W2[i]);
    } else if (i < 18432) {
      int j = i - 16384;  // 16x128 padded W3
      w3b[j] = (j < 1280) ? f2bf(W3[j]) : 0;
    }
    return;
  }
  for (int i = threadIdx.x; i < NB; i += blockDim.x) h[i] = 0;
  __syncthreads();
  int chunk = (E + 255) / 256;
  int e0 = blk * chunk;
  int e1 = min(e0 + chunk, E);
  for (int e = e0 + (int)threadIdx.x; e < e1; e += blockDim.x)
    atomicAdd(&h[ei[E + e] >> 7], 1);
  __syncthreads();
  for (int i = threadIdx.x; i < NB; i += blockDim.x)
    bhist[blk * NB + i] = h[i];
}

// ---------- fp32 -> bf16 cast ----------
__global__ void cvt_bf16(const float* __restrict__ x,
                         unsigned short* __restrict__ o, long long n) {
  long long i = ((long long)blockIdx.x * blockDim.x + threadIdx.x) * 4;
  if (i < n) {
    float4 v = *(const float4*)(x + i);
    uint2 w;
    w.x = packbf2(v.x, v.y);
    w.y = packbf2(v.z, v.w);
    *(uint2*)(o + i) = w;
  }
}

// ---------- reduce replicated stats -> BN coefficients (one block) -----------
__global__ void __launch_bounds__(128)
bn_coef(const float* __restrict__ stats, const float* __restrict__ g,
        const float* __restrict__ be, float* __restrict__ coef, float invN) {
  int f = threadIdx.x;
  float sum = 0.f, sq = 0.f;
  for (int r = 0; r < SREP; ++r) {
    sum += stats[r * 256 + f];
    sq  += stats[r * 256 + 128 + f];
  }
  float mean = sum * invN;
  float var = sq * invN - mean * mean;
  float s = g[f] * rsqrtf(var + 1e-5f);
  coef[f] = s;
  coef[128 + f] = be[f] - mean * s;
}

// ---------- column scan: per-bucket exclusive scan over the 256 chunks -------
__global__ void __launch_bounds__(256)
colscan(const int* __restrict__ bhist, int* __restrict__ cbase,
        int* __restrict__ bcnt, int NB) {
  __shared__ int tmp[256];
  const int b = blockIdx.x;
  const int g = threadIdx.x;
  int v = bhist[g * NB + b];
  tmp[g] = v;
  __syncthreads();
  for (int off = 1; off < 256; off <<= 1) {
    int t = (g >= off) ? tmp[g - off] : 0;
    __syncthreads();
    tmp[g] += t;
    __syncthreads();
  }
  cbase[g * NB + b] = tmp[g] - v;  // exclusive
  if (g == 255) bcnt[b] = tmp[255];
}

// ---------- scan bucket counts (NB<=1024, single chunk) ----------
__global__ void scan_buckets(const int* __restrict__ cnt,
                             int* __restrict__ bstart, int n) {
  __shared__ int tmp[1024];
  int i = threadIdx.x;
  int v = (i < n) ? cnt[i] : 0;
  tmp[i] = v;
  __syncthreads();
  for (int off = 1; off < 1024; off <<= 1) {
    int t = (i >= off) ? tmp[i - off] : 0;
    __syncthreads();
    tmp[i] += t;
    __syncthreads();
  }
  if (i == 0) bstart[0] = 0;
  if (i < n) bstart[i + 1] = tmp[i];
}

// ---------- partition edges; block base from cbase (deterministic, 0 atomics)
__global__ void partition_edges(const int* __restrict__ ei,
                                const int* __restrict__ bstart,
                                const int* __restrict__ cbase,
                                unsigned int* __restrict__ part, int E, int NB) {
  __shared__ int base[NB_MAX];
  __shared__ int cur[NB_MAX];
  int chunk = (E + gridDim.x - 1) / gridDim.x;
  int e0 = blockIdx.x * chunk;
  int e1 = min(e0 + chunk, E);
  for (int i = threadIdx.x; i < NB; i += blockDim.x) {
    cur[i] = 0;
    base[i] = bstart[i] + cbase[blockIdx.x * NB + i];
  }
  __syncthreads();
  for (int e = e0 + (int)threadIdx.x; e < e1; e += blockDim.x) {
    int d = ei[E + e];
    int b = d >> 7;
    int slot = base[b] + atomicAdd(&cur[b], 1);
    part[slot] = (unsigned int)ei[e] | ((unsigned int)(d & 127) << 17);
  }
}

// ---------- counting-sort each bucket -> csr + rs ----------
__global__ void __launch_bounds__(256)
csr_fill(const unsigned int* __restrict__ part, const int* __restrict__ bstart,
         int* __restrict__ rs, int* __restrict__ csr, int N, int NB) {
  __shared__ int h[128];
  __shared__ int off[128];
  const int b = blockIdx.x;
  const int e0 = bstart[b], e1 = bstart[b + 1];
  const int tid = threadIdx.x;
  if (tid < 128) h[tid] = 0;
  __syncthreads();
  for (int i = e0 + tid; i < e1; i += 256)
    atomicAdd(&h[part[i] >> 17], 1);
  __syncthreads();
  if (tid < 128) off[tid] = h[tid];
  __syncthreads();
  for (int s = 1; s < 128; s <<= 1) {
    int v = (tid < 128 && tid >= s) ? off[tid - s] : 0;
    __syncthreads();
    if (tid < 128) off[tid] += v;
    __syncthreads();
  }
  if (tid < 128) {
    int excl = e0 + off[tid] - h[tid];
    int node = b * 128 + tid;
    if (node < N) rs[node] = excl;
    h[tid] = excl;  // reuse as cursor
  }
  if (b == NB - 1 && tid == 0) rs[N] = e1;
  __syncthreads();
  for (int i = e0 + tid; i < e1; i += 256) {
    unsigned int p = part[i];
    int slot = atomicAdd(&h[p >> 17], 1);
    csr[slot] = (int)(p & 0x1FFFF);
  }
}

// ---------- aggregation: agg[i] = t[i] + sum_j t[j], bf16, fp32 acc ----------
// one wave per node; 16 lanes x 16B cover a row; 4 edges per VMEM instruction
__global__ void __launch_bounds__(256)
csr_agg128(const unsigned short* __restrict__ t, const int* __restrict__ rs,
           const int* __restrict__ csr, unsigned short* __restrict__ agg,
           int N) {
  int node = blockIdx.x * 4 + (threadIdx.x >> 6);
  if (node >= N) return;
  const int lane = threadIdx.x & 63;
  const int q = lane >> 4;   // quarter 0..3 -> edge stride phase
  const int ql = lane & 15;  // lane within quarter
  const int c = ql * 8;      // bf16 column (16B per lane)
  float a0 = 0.f, a1 = 0.f, a2 = 0.f, a3 = 0.f;
  float a4 = 0.f, a5 = 0.f, a6 = 0.f, a7 = 0.f;
  const int b = rs[node], e = rs[node + 1];
  int i = b + q;
  for (; i + 4 < e; i += 8) {  // 2 independent 1KB gathers in flight
    int j0 = csr[i], j1 = csr[i + 4];
    uint4 v0 = *(const uint4*)(t + (long long)j0 * 128 + c);
    uint4 v1 = *(const uint4*)(t + (long long)j1 * 128 + c);
    a0 += bflo(v0.x) + bflo(v1.x);  a1 += bfhi(v0.x) + bfhi(v1.x);
    a2 += bflo(v0.y) + bflo(v1.y);  a3 += bfhi(v0.y) + bfhi(v1.y);
    a4 += bflo(v0.z) + bflo(v1.z);  a5 += bfhi(v0.z) + bfhi(v1.z);
    a6 += bflo(v0.w) + bflo(v1.w);  a7 += bfhi(v0.w) + bfhi(v1.w);
  }
  if (i < e) {
    int j = csr[i];
    uint4 v = *(const uint4*)(t + (long long)j * 128 + c);
    a0 += bflo(v.x);  a1 += bfhi(v.x);
    a2 += bflo(v.y);  a3 += bfhi(v.y);
    a4 += bflo(v.z);  a5 += bfhi(v.z);
    a6 += bflo(v.w);  a7 += bfhi(v.w);
  }
  a0 += __shfl_xor(a0, 16, 64);  a1 += __shfl_xor(a1, 16, 64);
  a2 += __shfl_xor(a2, 16, 64);  a3 += __shfl_xor(a3, 16, 64);
  a4 += __shfl_xor(a4, 16, 64);  a5 += __shfl_xor(a5, 16, 64);
  a6 += __shfl_xor(a6, 16, 64);  a7 += __shfl_xor(a7, 16, 64);
  a0 += __shfl_xor(a0, 32, 64);  a1 += __shfl_xor(a1, 32, 64);
  a2 += __shfl_xor(a2, 32, 64);  a3 += __shfl_xor(a3, 32, 64);
  a4 += __shfl_xor(a4, 32, 64);  a5 += __shfl_xor(a5, 32, 64);
  a6 += __shfl_xor(a6, 32, 64);  a7 += __shfl_xor(a7, 32, 64);
  if (q == 0) {
    uint4 sv = *(const uint4*)(t + (long long)node * 128 + c);  // self term
    uint4 w;
    w.x = packbf2(a0 + bflo(sv.x), a1 + bfhi(sv.x));
    w.y = packbf2(a2 + bflo(sv.y), a3 + bfhi(sv.y));
    w.z = packbf2(a4 + bflo(sv.z), a5 + bfhi(sv.z));
    w.w = packbf2(a6 + bflo(sv.w), a7 + bfhi(sv.w));
    *(uint4*)(agg + (long long)node * 128 + c) = w;
  }
}

// ---------- fused: agg[i] = relu(bn(h_i)) + sum_j relu(bn(h_j)) --------------
// BN coefficients precomputed by bn_coef (no per-block reduction)
__global__ void __launch_bounds__(256)
csr_agg128_bn(const unsigned short* __restrict__ t, const int* __restrict__ rs,
              const int* __restrict__ csr, const float* __restrict__ coef,
              unsigned short* __restrict__ agg, int N) {
  __shared__ float lsc[128], lsh[128];
  if (threadIdx.x < 128) {
    lsc[threadIdx.x] = coef[threadIdx.x];
    lsh[threadIdx.x] = coef[128 + threadIdx.x];
  }
  __syncthreads();
  int node = blockIdx.x * 4 + (threadIdx.x >> 6);
  if (node >= N) return;
  const int lane = threadIdx.x & 63;
  const int q = lane >> 4;
  const int ql = lane & 15;
  const int c = ql * 8;
  float sc0 = lsc[c], sc1 = lsc[c + 1], sc2 = lsc[c + 2], sc3 = lsc[c + 3];
  float sc4 = lsc[c + 4], sc5 = lsc[c + 5], sc6 = lsc[c + 6], sc7 = lsc[c + 7];
  float sh0 = lsh[c], sh1 = lsh[c + 1], sh2 = lsh[c + 2], sh3 = lsh[c + 3];
  float sh4 = lsh[c + 4], sh5 = lsh[c + 5], sh6 = lsh[c + 6], sh7 = lsh[c + 7];
  float a0 = 0.f, a1 = 0.f, a2 = 0.f, a3 = 0.f;
  float a4 = 0.f, a5 = 0.f, a6 = 0.f, a7 = 0.f;
  const int b = rs[node], e = rs[node + 1];
  for (int i = b + q; i < e; i += 4) {
    int j = csr[i];
    uint4 v = *(const uint4*)(t + (long long)j * 128 + c);
    a0 += fmaxf(fmaf(bflo(v.x), sc0, sh0), 0.f);
    a1 += fmaxf(fmaf(bfhi(v.x), sc1, sh1), 0.f);
    a2 += fmaxf(fmaf(bflo(v.y), sc2, sh2), 0.f);
    a3 += fmaxf(fmaf(bfhi(v.y), sc3, sh3), 0.f);
    a4 += fmaxf(fmaf(bflo(v.z), sc4, sh4), 0.f);
    a5 += fmaxf(fmaf(bfhi(v.z), sc5, sh5), 0.f);
    a6 += fmaxf(fmaf(bflo(v.w), sc6, sh6), 0.f);
    a7 += fmaxf(fmaf(bfhi(v.w), sc7, sh7), 0.f);
  }
  a0 += __shfl_xor(a0, 16, 64);  a1 += __shfl_xor(a1, 16, 64);
  a2 += __shfl_xor(a2, 16, 64);  a3 += __shfl_xor(a3, 16, 64);
  a4 += __shfl_xor(a4, 16, 64);  a5 += __shfl_xor(a5, 16, 64);
  a6 += __shfl_xor(a6, 16, 64);  a7 += __shfl_xor(a7, 16, 64);
  a0 += __shfl_xor(a0, 32, 64);  a1 += __shfl_xor(a1, 32, 64);
  a2 += __shfl_xor(a2, 32, 64);  a3 += __shfl_xor(a3, 32, 64);
  a4 += __shfl_xor(a4, 32, 64);  a5 += __shfl_xor(a5, 32, 64);
  a6 += __shfl_xor(a6, 32, 64);  a7 += __shfl_xor(a7, 32, 64);
  if (q == 0) {
    uint4 sv = *(const uint4*)(t + (long long)node * 128 + c);  // self, affine
    uint4 w;
    w.x = packbf2(a0 + fmaxf(fmaf(bflo(sv.x), sc0, sh0), 0.f),
                  a1 + fmaxf(fmaf(bfhi(sv.x), sc1, sh1), 0.f));
    w.y = packbf2(a2 + fmaxf(fmaf(bflo(sv.y), sc2, sh2), 0.f),
                  a3 + fmaxf(fmaf(bfhi(sv.y), sc3, sh3), 0.f));
    w.z = packbf2(a4 + fmaxf(fmaf(bflo(sv.z), sc4, sh4), 0.f),
                  a5 + fmaxf(fmaf(bfhi(sv.z), sc5, sh5), 0.f));
    w.w = packbf2(a6 + fmaxf(fmaf(bflo(sv.w), sc6, sh6), 0.f),
                  a7 + fmaxf(fmaf(bfhi(sv.w), sc7, sh7), 0.f));
    *(uint4*)(agg + (long long)node * 128 + c) = w;
  }
}

// ---------- layer-3 aggregation on bf16 y[N,16] (8 lanes/node) ----------
__global__ void __launch_bounds__(256)
csr_agg10b(const unsigned short* __restrict__ y, const int* __restrict__ rs,
           const int* __restrict__ csr, const float* __restrict__ b3,
           float* __restrict__ out, int N) {
  int t = blockIdx.x * blockDim.x + threadIdx.x;
  int node = t >> 3;
  int c = (t & 7) * 2;
  if (node >= N) return;
  unsigned int sv = *(const unsigned int*)(y + node * 16 + c);
  float a0 = bflo(sv), a1 = bfhi(sv);
  int b = rs[node], e = rs[node + 1];
  int i = b;
  for (; i + 3 < e; i += 4) {
    int j0 = csr[i], j1 = csr[i + 1], j2 = csr[i + 2], j3 = csr[i + 3];
    unsigned int v0 = *(const unsigned int*)(y + j0 * 16 + c);
    unsigned int v1 = *(const unsigned int*)(y + j1 * 16 + c);
    unsigned int v2 = *(const unsigned int*)(y + j2 * 16 + c);
    unsigned int v3 = *(const unsigned int*)(y + j3 * 16 + c);
    a0 += bflo(v0) + bflo(v1) + bflo(v2) + bflo(v3);
    a1 += bfhi(v0) + bfhi(v1) + bfhi(v2) + bfhi(v3);
  }
  for (; i < e; ++i) {
    unsigned int v = *(const unsigned int*)(y + csr[i] * 16 + c);
    a0 += bflo(v);
    a1 += bfhi(v);
  }
  if (c < 10) {
    float2 o;
    o.x = a0 + b3[c];
    o.y = a1 + b3[c + 1];
    *(float2*)(out + node * 10 + c) = o;  // 40*node+8*(c/2): 8B aligned
  }
}

// ---------- GEMM: h_bf16 = A_bf16 @ Wb^T + bias, fused BN stats --------------
// stats accumulated into SREP-replicated buffers (spreads atomic contention)
__global__ void __launch_bounds__(256)
gemm128(const unsigned short* __restrict__ Ab, const unsigned short* __restrict__ Wb,
        const float* __restrict__ bias, unsigned short* __restrict__ Hb,
        float* __restrict__ stats, int M) {
  __shared__ __align__(16) unsigned short sA[128 * LDA];
  __shared__ __align__(16) unsigned short sB[128 * LDA];
  __shared__ float sSum[128], sSq[128];
  const int tid = threadIdx.x;
  const int row0 = blockIdx.x * 128;

  if (tid < 128) { sSum[tid] = 0.f; sSq[tid] = 0.f; }
  for (int j = 0; j < 8; ++j) {
    int flat = j * 2048 + tid * 8;
    int r = flat >> 7, c = flat & 127;
    int gr = row0 + r;
    uint4 v = make_uint4(0, 0, 0, 0);
    if (gr < M) v = *(const uint4*)(Ab + (long long)gr * 128 + c);
    *(uint4*)(sA + r * LDA + c) = v;
  }
  for (int j = 0; j < 8; ++j) {  // W already bf16: straight copies
    int flat = j * 2048 + tid * 8;
    int r = flat >> 7, c = flat & 127;
    *(uint4*)(sB + r * LDA + c) = *(const uint4*)(Wb + flat);
  }
  __syncthreads();

  const int lane = tid & 63, wid = tid >> 6;
  const int wM = (wid >> 1) * 64, wN = (wid & 1) * 64;
  const int l15 = lane & 15, quad = lane >> 4;
  f32x4 acc[4][4] = {};

  for (int kk = 0; kk < 4; ++kk) {
    const int kb = kk * 32 + quad * 8;
    bf16x8 af[4], bfr[4];
    for (int mi = 0; mi < 4; ++mi)
      af[mi] = *reinterpret_cast<const bf16x8*>(sA + (wM + mi * 16 + l15) * LDA + kb);
    for (int ni = 0; ni < 4; ++ni)
      bfr[ni] = *reinterpret_cast<const bf16x8*>(sB + (wN + ni * 16 + l15) * LDA + kb);
    for (int mi = 0; mi < 4; ++mi)
      for (int ni = 0; ni < 4; ++ni)
        acc[mi][ni] = __builtin_amdgcn_mfma_f32_16x16x32_bf16(
            af[mi], bfr[ni], acc[mi][ni], 0, 0, 0);
  }
  __syncthreads();  // done with sA as A-tile; reuse as C staging

  for (int ni = 0; ni < 4; ++ni) {
    int col = wN + ni * 16 + l15;
    float bv = bias[col];
    float s = 0.f, q = 0.f;
    for (int mi = 0; mi < 4; ++mi) {
      int rloc = wM + mi * 16 + quad * 4;
      for (int r = 0; r < 4; ++r) {
        if (row0 + rloc + r < M) {
          float v = acc[mi][ni][r] + bv;
          sA[(rloc + r) * LDA + col] = f2bf(v);
          s += v;
          q += v * v;
        }
      }
    }
    atomicAdd(&sSum[col], s);
    atomicAdd(&sSq[col], q);
  }
  __syncthreads();
  if (tid < 128) {
    float* st = stats + ((blockIdx.x & (SREP - 1)) << 8);
    atomicAdd(&st[tid], sSum[tid]);
    atomicAdd(&st[128 + tid], sSq[tid]);
  }
  for (int j = 0; j < 8; ++j) {  // coalesced 16B stores
    int flat = j * 2048 + tid * 8;
    int r = flat >> 7, c = flat & 127;
    int gr = row0 + r;
    if (gr < M)
      *(uint4*)(Hb + (long long)gr * 128 + c) = *(const uint4*)(sA + r * LDA + c);
  }
}

// ---------- y = relu(bn(h)) @ w3b^T, affine (from coef) fused into A-staging -
__global__ void __launch_bounds__(256)
gemm_y_bn(const unsigned short* __restrict__ Hb, const unsigned short* __restrict__ w3b,
          const float* __restrict__ coef, unsigned short* __restrict__ Y, int M) {
  __shared__ __align__(16) unsigned short sA[128 * LDA];
  __shared__ __align__(16) unsigned short sB[16 * LDA];
  __shared__ float lsc[128], lsh[128];
  const int tid = threadIdx.x;
  const int row0 = blockIdx.x * 128;

  if (tid < 128) {
    lsc[tid] = coef[tid];
    lsh[tid] = coef[128 + tid];
  }
  __syncthreads();
  for (int j = 0; j < 8; ++j) {
    int flat = j * 2048 + tid * 8;
    int r = flat >> 7, c = flat & 127;
    int gr = row0 + r;
    uint4 v = make_uint4(0, 0, 0, 0);
    if (gr < M) v = *(const uint4*)(Hb + (long long)gr * 128 + c);
    uint4 w;
    w.x = packbf2(fmaxf(fmaf(bflo(v.x), lsc[c + 0], lsh[c + 0]), 0.f),
                  fmaxf(fmaf(bfhi(v.x), lsc[c + 1], lsh[c + 1]), 0.f));
    w.y = packbf2(fmaxf(fmaf(bflo(v.y), lsc[c + 2], lsh[c + 2]), 0.f),
                  fmaxf(fmaf(bfhi(v.y), lsc[c + 3], lsh[c + 3]), 0.f));
    w.z = packbf2(fmaxf(fmaf(bflo(v.z), lsc[c + 4], lsh[c + 4]), 0.f),
                  fmaxf(fmaf(bfhi(v.z), lsc[c + 5], lsh[c + 5]), 0.f));
    w.w = packbf2(fmaxf(fmaf(bflo(v.w), lsc[c + 6], lsh[c + 6]), 0.f),
                  fmaxf(fmaf(bfhi(v.w), lsc[c + 7], lsh[c + 7]), 0.f));
    *(uint4*)(sA + r * LDA + c) = w;
  }
  {
    int flat = tid * 8;
    int r = flat >> 7, c = flat & 127;
    *(uint4*)(sB + r * LDA + c) = *(const uint4*)(w3b + flat);
  }
  __syncthreads();

  const int lane = tid & 63, wid = tid >> 6;
  const int l15 = lane & 15, quad = lane >> 4;
  f32x4 acc[2] = {};
  for (int kk = 0; kk < 4; ++kk) {
    const int kb = kk * 32 + quad * 8;
    bf16x8 b = *reinterpret_cast<const bf16x8*>(sB + l15 * LDA + kb);
    for (int mi = 0; mi < 2; ++mi) {
      bf16x8 a = *reinterpret_cast<const bf16x8*>(
          sA + (wid * 32 + mi * 16 + l15) * LDA + kb);
      acc[mi] = __builtin_amdgcn_mfma_f32_16x16x32_bf16(a, b, acc[mi], 0, 0, 0);
    }
  }
  __syncthreads();  // reuse sA as 128x16 C staging (stride 16)
  for (int mi = 0; mi < 2; ++mi)
    for (int r = 0; r < 4; ++r) {
      int rloc = wid * 32 + mi * 16 + quad * 4 + r;
      sA[rloc * 16 + l15] = (l15 < 10) ? f2bf(acc[mi][r]) : 0;
    }
  __syncthreads();
  {
    int flat = tid * 8;
    int gr = row0 + (flat >> 4);
    if (gr < M) *(uint4*)(Y + (long long)gr * 16 + (flat & 15)) =
        *(const uint4*)(sA + flat);
  }
}

// ---------- host ----------
extern "C" void kernel_launch(void* const* d_in, const int* in_sizes, int n_in,
                              void* d_out, int out_size, void* d_ws,
                              size_t ws_size, hipStream_t stream) {
  const float* x  = (const float*)d_in[0];
  const int*   ei = (const int*)d_in[1];  // int32 per harness contract
  const float* W1 = (const float*)d_in[2];
  const float* b1 = (const float*)d_in[3];
  const float* g1 = (const float*)d_in[4];
  const float* be1 = (const float*)d_in[5];
  const float* W2 = (const float*)d_in[6];
  const float* b2 = (const float*)d_in[7];
  const float* g2 = (const float*)d_in[8];
  const float* be2 = (const float*)d_in[9];
  const float* W3 = (const float*)d_in[10];
  const float* b3 = (const float*)d_in[11];

  const int N = in_sizes[0] / 128;
  const int E = in_sizes[1] / 2;
  const int NB = (N + 127) / 128;  // 128-node buckets

  // workspace layout (~91 MB); 16B-aligned arrays first
  unsigned short* featb = (unsigned short*)d_ws;              // N*128 bf16
  unsigned short* aggb  = featb + (size_t)N * 128;            // N*128 bf16
  unsigned short* hb    = aggb + (size_t)N * 128;             // N*128 bf16
  unsigned short* w1b   = hb + (size_t)N * 128;               // 16384
  unsigned short* w2b   = w1b + 16384;                        // 16384
  unsigned short* w3b   = w2b + 16384;                        // 2048
  int*   csr = (int*)(w3b + 2048);                            // E ints
  int*   rs  = csr + E;                                       // N+1
  int* bcnt  = rs + N + 1;                                    // NB
  int* bstart = bcnt + NB;                                    // NB+1
  int* bhist = bstart + NB + 1;                               // 256*NB
  float* stats1 = (float*)(bhist + 256 * NB);                 // SREP*256
  float* stats2 = stats1 + SREP * 256;                        // SREP*256
  float* coef1  = stats2 + SREP * 256;                        // 256
  float* coef2  = coef1 + 256;                                // 256
  // aliases into the (currently dead) hb region:
  unsigned int* part = (unsigned int*)hb;             // E uints (12.8 MB)
  int* cbase = (int*)(hb + (size_t)E * 2);            // 256*NB ints (~0.8 MB)
  unsigned short* y = featb;  // aliases featb (free in layer 3)
  float* out = (float*)d_out;

  const int TPB = 256;
  const int cvtBlocks   = (int)(((long long)N * 32 + TPB - 1) / TPB);
  const int aggBlocks   = (N + 3) / 4;   // one wave per node
  const int agg10Blocks = (N * 8 + TPB - 1) / TPB;
  const int gemmBlocks  = (N + 127) / 128;
  const float invN = 1.0f / (float)N;

  // ---- build: weights + CSR (atomic-free global phase) ----
  prep_hist<<<328, TPB, 0, stream>>>(W1, W2, W3, w1b, w2b, w3b, stats1, stats2,
                                     ei, bhist, E, NB);
  colscan<<<NB, TPB, 0, stream>>>(bhist, cbase, bcnt, NB);
  scan_buckets<<<1, 1024, 0, stream>>>(bcnt, bstart, NB);
  partition_edges<<<256, TPB, 0, stream>>>(ei, bstart, cbase, part, E, NB);
  csr_fill<<<NB, TPB, 0, stream>>>(part, bstart, rs, csr, N, NB);

  // ---- layer 1 ----
  cvt_bf16<<<cvtBlocks, TPB, 0, stream>>>(x, featb, (long long)N * 128);
  csr_agg128<<<aggBlocks, TPB, 0, stream>>>(featb, rs, csr, aggb, N);
  gemm128<<<gemmBlocks, TPB, 0, stream>>>(aggb, w1b, b1, hb, stats1, N);

  // ---- layer 2 (BN1 coefficients reduced once; BN+ReLU fused into agg) ----
  bn_coef<<<1, 128, 0, stream>>>(stats1, g1, be1, coef1, invN);
  csr_agg128_bn<<<aggBlocks, TPB, 0, stream>>>(hb, rs, csr, coef1, aggb, N);
  gemm128<<<gemmBlocks, TPB, 0, stream>>>(aggb, w2b, b2, hb, stats2, N);

  // ---- layer 3 (BN2 via coef; BN+ReLU fused into gemm_y A-staging) ----
  bn_coef<<<1, 128, 0, stream>>>(stats2, g2, be2, coef2, invN);
  gemm_y_bn<<<gemmBlocks, TPB, 0, stream>>>(hb, w3b, coef2, y, N);
  csr_agg10b<<<agg10Blocks, TPB, 0, stream>>>(y, rs, csr, b3, out, N);
}

// Round 11
// 548.311 us; speedup vs baseline: 1.0676x; 1.0113x over previous
//
#include <hip/hip_runtime.h>

typedef __bf16 bf16x8 __attribute__((ext_vector_type(8)));
typedef float  f32x4  __attribute__((ext_vector_type(4)));

#define LDA 136       // padded bf16 row stride for GEMM LDS tiles
#define NB_MAX 2048   // max 64-node buckets (N<=131072)
#define CH 512        // histogram/partition chunk count (2 blocks/CU)
#define SREP 32       // stats replication factor (spreads atomic contention)

static __device__ __forceinline__ unsigned short f2bf(float f) {
  unsigned int u = __float_as_uint(f);
  u += 0x7fffu + ((u >> 16) & 1u);
  return (unsigned short)(u >> 16);
}
static __device__ __forceinline__ float bflo(unsigned int u) {
  return __uint_as_float(u << 16);
}
static __device__ __forceinline__ float bfhi(unsigned int u) {
  return __uint_as_float(u & 0xFFFF0000u);
}
static __device__ __forceinline__ unsigned int packbf2(float a, float b) {
  return (unsigned int)f2bf(a) | ((unsigned int)f2bf(b) << 16);
}

// ---------- fused prep (weights->bf16, zero stats) + bucket histogram --------
// blocks 0..CH-1: histogram chunks (bucket = dst >> 6); blocks CH..CH+71: prep
__global__ void prep_hist(const float* __restrict__ W1, const float* __restrict__ W2,
                          const float* __restrict__ W3, unsigned short* __restrict__ w1b,
                          unsigned short* __restrict__ w2b, unsigned short* __restrict__ w3b,
                          float* __restrict__ s1, float* __restrict__ s2,
                          const int* __restrict__ ei, int* __restrict__ bhist,
                          int E, int NB) {
  __shared__ int h[NB_MAX];
  const int blk = blockIdx.x;
  if (blk >= CH) {  // prep branch (uniform per block; no barrier divergence)
    int i = (blk - CH) * 256 + threadIdx.x;
    if (i < SREP * 256) { s1[i] = 0.f; s2[i] = 0.f; }
    if (i < 16384) {
      w1b[i] = f2bf(W1[i]);
      w2b[i] = f2bf(W2[i]);
    } else if (i < 18432) {
      int j = i - 16384;  // 16x128 padded W3
      w3b[j] = (j < 1280) ? f2bf(W3[j]) : 0;
    }
    return;
  }
  for (int i = threadIdx.x; i < NB; i += blockDim.x) h[i] = 0;
  __syncthreads();
  int chunk = (E + CH - 1) / CH;
  int e0 = blk * chunk;
  int e1 = min(e0 + chunk, E);
  for (int e = e0 + (int)threadIdx.x; e < e1; e += blockDim.x)
    atomicAdd(&h[ei[E + e] >> 6], 1);
  __syncthreads();
  for (int i = threadIdx.x; i < NB; i += blockDim.x)
    bhist[blk * NB + i] = h[i];
}

// ---------- fp32 -> bf16 cast ----------
__global__ void cvt_bf16(const float* __restrict__ x,
                         unsigned short* __restrict__ o, long long n) {
  long long i = ((long long)blockIdx.x * blockDim.x + threadIdx.x) * 4;
  if (i < n) {
    float4 v = *(const float4*)(x + i);
    uint2 w;
    w.x = packbf2(v.x, v.y);
    w.y = packbf2(v.z, v.w);
    *(uint2*)(o + i) = w;
  }
}

// ---------- reduce replicated stats -> BN coefficients (one block) -----------
__global__ void __launch_bounds__(128)
bn_coef(const float* __restrict__ stats, const float* __restrict__ g,
        const float* __restrict__ be, float* __restrict__ coef, float invN) {
  int f = threadIdx.x;
  float sum = 0.f, sq = 0.f;
  for (int r = 0; r < SREP; ++r) {
    sum += stats[r * 256 + f];
    sq  += stats[r * 256 + 128 + f];
  }
  float mean = sum * invN;
  float var = sq * invN - mean * mean;
  float s = g[f] * rsqrtf(var + 1e-5f);
  coef[f] = s;
  coef[128 + f] = be[f] - mean * s;
}

// ---------- column scan: per-bucket exclusive scan over the CH chunks --------
// 256 threads handle 2 chunks each (2g, 2g+1)
__global__ void __launch_bounds__(256)
colscan(const int* __restrict__ bhist, int* __restrict__ cbase,
        int* __restrict__ bcnt, int NB) {
  __shared__ int tmp[256];
  const int b = blockIdx.x;
  const int g = threadIdx.x;
  int v0 = bhist[(2 * g) * NB + b];
  int v1 = bhist[(2 * g + 1) * NB + b];
  int pair = v0 + v1;
  tmp[g] = pair;
  __syncthreads();
  for (int off = 1; off < 256; off <<= 1) {
    int t = (g >= off) ? tmp[g - off] : 0;
    __syncthreads();
    tmp[g] += t;
    __syncthreads();
  }
  int excl = tmp[g] - pair;
  cbase[(2 * g) * NB + b] = excl;
  cbase[(2 * g + 1) * NB + b] = excl + v0;
  if (g == 255) bcnt[b] = tmp[255];
}

// ---------- scan bucket counts (n<=2048, 1024 threads x 2 elements) ----------
__global__ void scan_buckets(const int* __restrict__ cnt,
                             int* __restrict__ bstart, int n) {
  __shared__ int tmp[1024];
  int i = threadIdx.x;
  int a = (2 * i < n) ? cnt[2 * i] : 0;
  int b = (2 * i + 1 < n) ? cnt[2 * i + 1] : 0;
  int pair = a + b;
  tmp[i] = pair;
  __syncthreads();
  for (int off = 1; off < 1024; off <<= 1) {
    int t = (i >= off) ? tmp[i - off] : 0;
    __syncthreads();
    tmp[i] += t;
    __syncthreads();
  }
  int excl = tmp[i] - pair;
  if (i == 0) bstart[0] = 0;
  if (2 * i < n) bstart[2 * i + 1] = excl + a;
  if (2 * i + 1 < n) bstart[2 * i + 2] = excl + a + b;
}

// ---------- partition edges; block base from cbase (deterministic, 0 atomics)
__global__ void partition_edges(const int* __restrict__ ei,
                                const int* __restrict__ bstart,
                                const int* __restrict__ cbase,
                                unsigned int* __restrict__ part, int E, int NB) {
  __shared__ int base[NB_MAX];
  __shared__ int cur[NB_MAX];
  int chunk = (E + gridDim.x - 1) / gridDim.x;
  int e0 = blockIdx.x * chunk;
  int e1 = min(e0 + chunk, E);
  for (int i = threadIdx.x; i < NB; i += blockDim.x) {
    cur[i] = 0;
    base[i] = bstart[i] + cbase[blockIdx.x * NB + i];
  }
  __syncthreads();
  for (int e = e0 + (int)threadIdx.x; e < e1; e += blockDim.x) {
    int d = ei[E + e];
    int b = d >> 6;
    int slot = base[b] + atomicAdd(&cur[b], 1);
    part[slot] = (unsigned int)ei[e] | ((unsigned int)(d & 63) << 17);
  }
}

// ---------- counting-sort each 64-node bucket -> csr + rs ----------
__global__ void __launch_bounds__(256)
csr_fill(const unsigned int* __restrict__ part, const int* __restrict__ bstart,
         int* __restrict__ rs, int* __restrict__ csr, int N, int NB) {
  __shared__ int h[64];
  __shared__ int off[64];
  const int b = blockIdx.x;
  const int e0 = bstart[b], e1 = bstart[b + 1];
  const int tid = threadIdx.x;
  if (tid < 64) h[tid] = 0;
  __syncthreads();
  for (int i = e0 + tid; i < e1; i += 256)
    atomicAdd(&h[part[i] >> 17], 1);
  __syncthreads();
  if (tid < 64) off[tid] = h[tid];
  __syncthreads();
  for (int s = 1; s < 64; s <<= 1) {
    int v = (tid < 64 && tid >= s) ? off[tid - s] : 0;
    __syncthreads();
    if (tid < 64) off[tid] += v;
    __syncthreads();
  }
  if (tid < 64) {
    int excl = e0 + off[tid] - h[tid];
    int node = b * 64 + tid;
    if (node < N) rs[node] = excl;
    h[tid] = excl;  // reuse as cursor
  }
  if (b == NB - 1 && tid == 0) rs[N] = e1;
  __syncthreads();
  for (int i = e0 + tid; i < e1; i += 256) {
    unsigned int p = part[i];
    int slot = atomicAdd(&h[p >> 17], 1);
    csr[slot] = (int)(p & 0x1FFFF);
  }
}

// ---------- aggregation: agg[i] = t[i] + sum_j t[j], bf16, fp32 acc ----------
// one wave per node; 16 lanes x 16B cover a row; 4 edges per VMEM instruction
__global__ void __launch_bounds__(256)
csr_agg128(const unsigned short* __restrict__ t, const int* __restrict__ rs,
           const int* __restrict__ csr, unsigned short* __restrict__ agg,
           int N) {
  int node = blockIdx.x * 4 + (threadIdx.x >> 6);
  if (node >= N) return;
  const int lane = threadIdx.x & 63;
  const int q = lane >> 4;   // quarter 0..3 -> edge stride phase
  const int ql = lane & 15;  // lane within quarter
  const int c = ql * 8;      // bf16 column (16B per lane)
  float a0 = 0.f, a1 = 0.f, a2 = 0.f, a3 = 0.f;
  float a4 = 0.f, a5 = 0.f, a6 = 0.f, a7 = 0.f;
  const int b = rs[node], e = rs[node + 1];
  int i = b + q;
  for (; i + 4 < e; i += 8) {  // 2 independent 1KB gathers in flight
    int j0 = csr[i], j1 = csr[i + 4];
    uint4 v0 = *(const uint4*)(t + (long long)j0 * 128 + c);
    uint4 v1 = *(const uint4*)(t + (long long)j1 * 128 + c);
    a0 += bflo(v0.x) + bflo(v1.x);  a1 += bfhi(v0.x) + bfhi(v1.x);
    a2 += bflo(v0.y) + bflo(v1.y);  a3 += bfhi(v0.y) + bfhi(v1.y);
    a4 += bflo(v0.z) + bflo(v1.z);  a5 += bfhi(v0.z) + bfhi(v1.z);
    a6 += bflo(v0.w) + bflo(v1.w);  a7 += bfhi(v0.w) + bfhi(v1.w);
  }
  if (i < e) {
    int j = csr[i];
    uint4 v = *(const uint4*)(t + (long long)j * 128 + c);
    a0 += bflo(v.x);  a1 += bfhi(v.x);
    a2 += bflo(v.y);  a3 += bfhi(v.y);
    a4 += bflo(v.z);  a5 += bfhi(v.z);
    a6 += bflo(v.w);  a7 += bfhi(v.w);
  }
  a0 += __shfl_xor(a0, 16, 64);  a1 += __shfl_xor(a1, 16, 64);
  a2 += __shfl_xor(a2, 16, 64);  a3 += __shfl_xor(a3, 16, 64);
  a4 += __shfl_xor(a4, 16, 64);  a5 += __shfl_xor(a5, 16, 64);
  a6 += __shfl_xor(a6, 16, 64);  a7 += __shfl_xor(a7, 16, 64);
  a0 += __shfl_xor(a0, 32, 64);  a1 += __shfl_xor(a1, 32, 64);
  a2 += __shfl_xor(a2, 32, 64);  a3 += __shfl_xor(a3, 32, 64);
  a4 += __shfl_xor(a4, 32, 64);  a5 += __shfl_xor(a5, 32, 64);
  a6 += __shfl_xor(a6, 32, 64);  a7 += __shfl_xor(a7, 32, 64);
  if (q == 0) {
    uint4 sv = *(const uint4*)(t + (long long)node * 128 + c);  // self term
    uint4 w;
    w.x = packbf2(a0 + bflo(sv.x), a1 + bfhi(sv.x));
    w.y = packbf2(a2 + bflo(sv.y), a3 + bfhi(sv.y));
    w.z = packbf2(a4 + bflo(sv.z), a5 + bfhi(sv.z));
    w.w = packbf2(a6 + bflo(sv.w), a7 + bfhi(sv.w));
    *(uint4*)(agg + (long long)node * 128 + c) = w;
  }
}

// ---------- fused: agg[i] = relu(bn(h_i)) + sum_j relu(bn(h_j)) --------------
// BN coefficients precomputed by bn_coef (no per-block reduction)
__global__ void __launch_bounds__(256)
csr_agg128_bn(const unsigned short* __restrict__ t, const int* __restrict__ rs,
              const int* __restrict__ csr, const float* __restrict__ coef,
              unsigned short* __restrict__ agg, int N) {
  __shared__ float lsc[128], lsh[128];
  if (threadIdx.x < 128) {
    lsc[threadIdx.x] = coef[threadIdx.x];
    lsh[threadIdx.x] = coef[128 + threadIdx.x];
  }
  __syncthreads();
  int node = blockIdx.x * 4 + (threadIdx.x >> 6);
  if (node >= N) return;
  const int lane = threadIdx.x & 63;
  const int q = lane >> 4;
  const int ql = lane & 15;
  const int c = ql * 8;
  float sc0 = lsc[c], sc1 = lsc[c + 1], sc2 = lsc[c + 2], sc3 = lsc[c + 3];
  float sc4 = lsc[c + 4], sc5 = lsc[c + 5], sc6 = lsc[c + 6], sc7 = lsc[c + 7];
  float sh0 = lsh[c], sh1 = lsh[c + 1], sh2 = lsh[c + 2], sh3 = lsh[c + 3];
  float sh4 = lsh[c + 4], sh5 = lsh[c + 5], sh6 = lsh[c + 6], sh7 = lsh[c + 7];
  float a0 = 0.f, a1 = 0.f, a2 = 0.f, a3 = 0.f;
  float a4 = 0.f, a5 = 0.f, a6 = 0.f, a7 = 0.f;
  const int b = rs[node], e = rs[node + 1];
  for (int i = b + q; i < e; i += 4) {
    int j = csr[i];
    uint4 v = *(const uint4*)(t + (long long)j * 128 + c);
    a0 += fmaxf(fmaf(bflo(v.x), sc0, sh0), 0.f);
    a1 += fmaxf(fmaf(bfhi(v.x), sc1, sh1), 0.f);
    a2 += fmaxf(fmaf(bflo(v.y), sc2, sh2), 0.f);
    a3 += fmaxf(fmaf(bfhi(v.y), sc3, sh3), 0.f);
    a4 += fmaxf(fmaf(bflo(v.z), sc4, sh4), 0.f);
    a5 += fmaxf(fmaf(bfhi(v.z), sc5, sh5), 0.f);
    a6 += fmaxf(fmaf(bflo(v.w), sc6, sh6), 0.f);
    a7 += fmaxf(fmaf(bfhi(v.w), sc7, sh7), 0.f);
  }
  a0 += __shfl_xor(a0, 16, 64);  a1 += __shfl_xor(a1, 16, 64);
  a2 += __shfl_xor(a2, 16, 64);  a3 += __shfl_xor(a3, 16, 64);
  a4 += __shfl_xor(a4, 16, 64);  a5 += __shfl_xor(a5, 16, 64);
  a6 += __shfl_xor(a6, 16, 64);  a7 += __shfl_xor(a7, 16, 64);
  a0 += __shfl_xor(a0, 32, 64);  a1 += __shfl_xor(a1, 32, 64);
  a2 += __shfl_xor(a2, 32, 64);  a3 += __shfl_xor(a3, 32, 64);
  a4 += __shfl_xor(a4, 32, 64);  a5 += __shfl_xor(a5, 32, 64);
  a6 += __shfl_xor(a6, 32, 64);  a7 += __shfl_xor(a7, 32, 64);
  if (q == 0) {
    uint4 sv = *(const uint4*)(t + (long long)node * 128 + c);  // self, affine
    uint4 w;
    w.x = packbf2(a0 + fmaxf(fmaf(bflo(sv.x), sc0, sh0), 0.f),
                  a1 + fmaxf(fmaf(bfhi(sv.x), sc1, sh1), 0.f));
    w.y = packbf2(a2 + fmaxf(fmaf(bflo(sv.y), sc2, sh2), 0.f),
                  a3 + fmaxf(fmaf(bfhi(sv.y), sc3, sh3), 0.f));
    w.z = packbf2(a4 + fmaxf(fmaf(bflo(sv.z), sc4, sh4), 0.f),
                  a5 + fmaxf(fmaf(bfhi(sv.z), sc5, sh5), 0.f));
    w.w = packbf2(a6 + fmaxf(fmaf(bflo(sv.w), sc6, sh6), 0.f),
                  a7 + fmaxf(fmaf(bfhi(sv.w), sc7, sh7), 0.f));
    *(uint4*)(agg + (long long)node * 128 + c) = w;
  }
}

// ---------- layer-3 aggregation on bf16 y[N,16] (8 lanes/node) ----------
__global__ void __launch_bounds__(256)
csr_agg10b(const unsigned short* __restrict__ y, const int* __restrict__ rs,
           const int* __restrict__ csr, const float* __restrict__ b3,
           float* __restrict__ out, int N) {
  int t = blockIdx.x * blockDim.x + threadIdx.x;
  int node = t >> 3;
  int c = (t & 7) * 2;
  if (node >= N) return;
  unsigned int sv = *(const unsigned int*)(y + node * 16 + c);
  float a0 = bflo(sv), a1 = bfhi(sv);
  int b = rs[node], e = rs[node + 1];
  int i = b;
  for (; i + 3 < e; i += 4) {
    int j0 = csr[i], j1 = csr[i + 1], j2 = csr[i + 2], j3 = csr[i + 3];
    unsigned int v0 = *(const unsigned int*)(y + j0 * 16 + c);
    unsigned int v1 = *(const unsigned int*)(y + j1 * 16 + c);
    unsigned int v2 = *(const unsigned int*)(y + j2 * 16 + c);
    unsigned int v3 = *(const unsigned int*)(y + j3 * 16 + c);
    a0 += bflo(v0) + bflo(v1) + bflo(v2) + bflo(v3);
    a1 += bfhi(v0) + bfhi(v1) + bfhi(v2) + bfhi(v3);
  }
  for (; i < e; ++i) {
    unsigned int v = *(const unsigned int*)(y + csr[i] * 16 + c);
    a0 += bflo(v);
    a1 += bfhi(v);
  }
  if (c < 10) {
    float2 o;
    o.x = a0 + b3[c];
    o.y = a1 + b3[c + 1];
    *(float2*)(out + node * 10 + c) = o;  // 40*node+8*(c/2): 8B aligned
  }
}

// ---------- GEMM: h_bf16 = A_bf16 @ Wb^T + bias, fused BN stats --------------
// stats accumulated into SREP-replicated buffers (spreads atomic contention)
__global__ void __launch_bounds__(256)
gemm128(const unsigned short* __restrict__ Ab, const unsigned short* __restrict__ Wb,
        const float* __restrict__ bias, unsigned short* __restrict__ Hb,
        float* __restrict__ stats, int M) {
  __shared__ __align__(16) unsigned short sA[128 * LDA];
  __shared__ __align__(16) unsigned short sB[128 * LDA];
  __shared__ float sSum[128], sSq[128];
  const int tid = threadIdx.x;
  const int row0 = blockIdx.x * 128;

  if (tid < 128) { sSum[tid] = 0.f; sSq[tid] = 0.f; }
  for (int j = 0; j < 8; ++j) {
    int flat = j * 2048 + tid * 8;
    int r = flat >> 7, c = flat & 127;
    int gr = row0 + r;
    uint4 v = make_uint4(0, 0, 0, 0);
    if (gr < M) v = *(const uint4*)(Ab + (long long)gr * 128 + c);
    *(uint4*)(sA + r * LDA + c) = v;
  }
  for (int j = 0; j < 8; ++j) {  // W already bf16: straight copies
    int flat = j * 2048 + tid * 8;
    int r = flat >> 7, c = flat & 127;
    *(uint4*)(sB + r * LDA + c) = *(const uint4*)(Wb + flat);
  }
  __syncthreads();

  const int lane = tid & 63, wid = tid >> 6;
  const int wM = (wid >> 1) * 64, wN = (wid & 1) * 64;
  const int l15 = lane & 15, quad = lane >> 4;
  f32x4 acc[4][4] = {};

  for (int kk = 0; kk < 4; ++kk) {
    const int kb = kk * 32 + quad * 8;
    bf16x8 af[4], bfr[4];
    for (int mi = 0; mi < 4; ++mi)
      af[mi] = *reinterpret_cast<const bf16x8*>(sA + (wM + mi * 16 + l15) * LDA + kb);
    for (int ni = 0; ni < 4; ++ni)
      bfr[ni] = *reinterpret_cast<const bf16x8*>(sB + (wN + ni * 16 + l15) * LDA + kb);
    for (int mi = 0; mi < 4; ++mi)
      for (int ni = 0; ni < 4; ++ni)
        acc[mi][ni] = __builtin_amdgcn_mfma_f32_16x16x32_bf16(
            af[mi], bfr[ni], acc[mi][ni], 0, 0, 0);
  }
  __syncthreads();  // done with sA as A-tile; reuse as C staging

  for (int ni = 0; ni < 4; ++ni) {
    int col = wN + ni * 16 + l15;
    float bv = bias[col];
    float s = 0.f, q = 0.f;
    for (int mi = 0; mi < 4; ++mi) {
      int rloc = wM + mi * 16 + quad * 4;
      for (int r = 0; r < 4; ++r) {
        if (row0 + rloc + r < M) {
          float v = acc[mi][ni][r] + bv;
          sA[(rloc + r) * LDA + col] = f2bf(v);
          s += v;
          q += v * v;
        }
      }
    }
    atomicAdd(&sSum[col], s);
    atomicAdd(&sSq[col], q);
  }
  __syncthreads();
  if (tid < 128) {
    float* st = stats + ((blockIdx.x & (SREP - 1)) << 8);
    atomicAdd(&st[tid], sSum[tid]);
    atomicAdd(&st[128 + tid], sSq[tid]);
  }
  for (int j = 0; j < 8; ++j) {  // coalesced 16B stores
    int flat = j * 2048 + tid * 8;
    int r = flat >> 7, c = flat & 127;
    int gr = row0 + r;
    if (gr < M)
      *(uint4*)(Hb + (long long)gr * 128 + c) = *(const uint4*)(sA + r * LDA + c);
  }
}

// ---------- y = relu(bn(h)) @ w3b^T, affine (from coef) fused into A-staging -
__global__ void __launch_bounds__(256)
gemm_y_bn(const unsigned short* __restrict__ Hb, const unsigned short* __restrict__ w3b,
          const float* __restrict__ coef, unsigned short* __restrict__ Y, int M) {
  __shared__ __align__(16) unsigned short sA[128 * LDA];
  __shared__ __align__(16) unsigned short sB[16 * LDA];
  __shared__ float lsc[128], lsh[128];
  const int tid = threadIdx.x;
  const int row0 = blockIdx.x * 128;

  if (tid < 128) {
    lsc[tid] = coef[tid];
    lsh[tid] = coef[128 + tid];
  }
  __syncthreads();
  for (int j = 0; j < 8; ++j) {
    int flat = j * 2048 + tid * 8;
    int r = flat >> 7, c = flat & 127;
    int gr = row0 + r;
    uint4 v = make_uint4(0, 0, 0, 0);
    if (gr < M) v = *(const uint4*)(Hb + (long long)gr * 128 + c);
    uint4 w;
    w.x = packbf2(fmaxf(fmaf(bflo(v.x), lsc[c + 0], lsh[c + 0]), 0.f),
                  fmaxf(fmaf(bfhi(v.x), lsc[c + 1], lsh[c + 1]), 0.f));
    w.y = packbf2(fmaxf(fmaf(bflo(v.y), lsc[c + 2], lsh[c + 2]), 0.f),
                  fmaxf(fmaf(bfhi(v.y), lsc[c + 3], lsh[c + 3]), 0.f));
    w.z = packbf2(fmaxf(fmaf(bflo(v.z), lsc[c + 4], lsh[c + 4]), 0.f),
                  fmaxf(fmaf(bfhi(v.z), lsc[c + 5], lsh[c + 5]), 0.f));
    w.w = packbf2(fmaxf(fmaf(bflo(v.w), lsc[c + 6], lsh[c + 6]), 0.f),
                  fmaxf(fmaf(bfhi(v.w), lsc[c + 7], lsh[c + 7]), 0.f));
    *(uint4*)(sA + r * LDA + c) = w;
  }
  {
    int flat = tid * 8;
    int r = flat >> 7, c = flat & 127;
    *(uint4*)(sB + r * LDA + c) = *(const uint4*)(w3b + flat);
  }
  __syncthreads();

  const int lane = tid & 63, wid = tid >> 6;
  const int l15 = lane & 15, quad = lane >> 4;
  f32x4 acc[2] = {};
  for (int kk = 0; kk < 4; ++kk) {
    const int kb = kk * 32 + quad * 8;
    bf16x8 b = *reinterpret_cast<const bf16x8*>(sB + l15 * LDA + kb);
    for (int mi = 0; mi < 2; ++mi) {
      bf16x8 a = *reinterpret_cast<const bf16x8*>(
          sA + (wid * 32 + mi * 16 + l15) * LDA + kb);
      acc[mi] = __builtin_amdgcn_mfma_f32_16x16x32_bf16(a, b, acc[mi], 0, 0, 0);
    }
  }
  __syncthreads();  // reuse sA as 128x16 C staging (stride 16)
  for (int mi = 0; mi < 2; ++mi)
    for (int r = 0; r < 4; ++r) {
      int rloc = wid * 32 + mi * 16 + quad * 4 + r;
      sA[rloc * 16 + l15] = (l15 < 10) ? f2bf(acc[mi][r]) : 0;
    }
  __syncthreads();
  {
    int flat = tid * 8;
    int gr = row0 + (flat >> 4);
    if (gr < M) *(uint4*)(Y + (long long)gr * 16 + (flat & 15)) =
        *(const uint4*)(sA + flat);
  }
}

// ---------- host ----------
extern "C" void kernel_launch(void* const* d_in, const int* in_sizes, int n_in,
                              void* d_out, int out_size, void* d_ws,
                              size_t ws_size, hipStream_t stream) {
  const float* x  = (const float*)d_in[0];
  const int*   ei = (const int*)d_in[1];  // int32 per harness contract
  const float* W1 = (const float*)d_in[2];
  const float* b1 = (const float*)d_in[3];
  const float* g1 = (const float*)d_in[4];
  const float* be1 = (const float*)d_in[5];
  const float* W2 = (const float*)d_in[6];
  const float* b2 = (const float*)d_in[7];
  const float* g2 = (const float*)d_in[8];
  const float* be2 = (const float*)d_in[9];
  const float* W3 = (const float*)d_in[10];
  const float* b3 = (const float*)d_in[11];

  const int N = in_sizes[0] / 128;
  const int E = in_sizes[1] / 2;
  const int NB = (N + 63) / 64;  // 64-node buckets (more csr_fill parallelism)

  // workspace layout (~90 MB, smaller than round-9's); 16B-aligned arrays first
  unsigned short* featb = (unsigned short*)d_ws;              // N*128 bf16
  unsigned short* aggb  = featb + (size_t)N * 128;            // N*128 bf16
  unsigned short* hb    = aggb + (size_t)N * 128;             // N*128 bf16
  unsigned short* w1b   = hb + (size_t)N * 128;               // 16384
  unsigned short* w2b   = w1b + 16384;                        // 16384
  unsigned short* w3b   = w2b + 16384;                        // 2048
  int*   csr = (int*)(w3b + 2048);                            // E ints
  int*   rs  = csr + E;                                       // N+1
  int* bcnt  = rs + N + 1;                                    // NB
  int* bstart = bcnt + NB;                                    // NB+1
  float* stats1 = (float*)(bstart + NB + 1);                  // SREP*256
  float* stats2 = stats1 + SREP * 256;                        // SREP*256
  float* coef1  = stats2 + SREP * 256;                        // 256
  float* coef2  = coef1 + 256;                                // 256
  // transient aliases into the hb region (dead until layer-1 gemm writes hb):
  // part (E uints, 12.8MB) + cbase (CH*NB, 3.2MB) + bhist (CH*NB, 3.2MB)
  //   = 19.2MB < 25.6MB region
  unsigned int* part = (unsigned int*)hb;
  int* cbase = (int*)(hb + (size_t)E * 2);
  int* bhist = cbase + (size_t)CH * NB;
  unsigned short* y = featb;  // aliases featb (free in layer 3)
  float* out = (float*)d_out;

  const int TPB = 256;
  const int cvtBlocks   = (int)(((long long)N * 32 + TPB - 1) / TPB);
  const int aggBlocks   = (N + 3) / 4;   // one wave per node
  const int agg10Blocks = (N * 8 + TPB - 1) / TPB;
  const int gemmBlocks  = (N + 127) / 128;
  const float invN = 1.0f / (float)N;

  // ---- build: weights + CSR (atomic-free global phase) ----
  prep_hist<<<CH + 72, TPB, 0, stream>>>(W1, W2, W3, w1b, w2b, w3b, stats1,
                                         stats2, ei, bhist, E, NB);
  colscan<<<NB, TPB, 0, stream>>>(bhist, cbase, bcnt, NB);
  scan_buckets<<<1, 1024, 0, stream>>>(bcnt, bstart, NB);
  partition_edges<<<CH, TPB, 0, stream>>>(ei, bstart, cbase, part, E, NB);
  csr_fill<<<NB, TPB, 0, stream>>>(part, bstart, rs, csr, N, NB);

  // ---- layer 1 ----
  cvt_bf16<<<cvtBlocks, TPB, 0, stream>>>(x, featb, (long long)N * 128);
  csr_agg128<<<aggBlocks, TPB, 0, stream>>>(featb, rs, csr, aggb, N);
  gemm128<<<gemmBlocks, TPB, 0, stream>>>(aggb, w1b, b1, hb, stats1, N);

  // ---- layer 2 (BN1 coefficients reduced once; BN+ReLU fused into agg) ----
  bn_coef<<<1, 128, 0, stream>>>(stats1, g1, be1, coef1, invN);
  csr_agg128_bn<<<aggBlocks, TPB, 0, stream>>>(hb, rs, csr, coef1, aggb, N);
  gemm128<<<gemmBlocks, TPB, 0, stream>>>(aggb, w2b, b2, hb, stats2, N);

  // ---- layer 3 (BN2 via coef; BN+ReLU fused into gemm_y A-staging) ----
  bn_coef<<<1, 128, 0, stream>>>(stats2, g2, be2, coef2, invN);
  gemm_y_bn<<<gemmBlocks, TPB, 0, stream>>>(hb, w3b, coef2, y, N);
  csr_agg10b<<<agg10Blocks, TPB, 0, stream>>>(y, rs, csr, b3, out, N);
}